// Round 2
// baseline (614.472 us; speedup 1.0000x reference)
//
#include <hip/hip_runtime.h>
#include <hip/hip_bf16.h>
#include <stdint.h>

// MegaNeRF fused MoE-MLP for MI355X (gfx950).  Round 2.
// E=8 experts, MLP 90->256->256->256->4, N=131072 points, inverse-distance gating.
//
// Round-2 changes vs round-1 (which passed at 492 us, MfmaUtil 28%, occ 24%):
//  - MT=64: LDS 70.6 KB -> 2 blocks/CU -> 4 waves/SIMD (occupancy 2x)
//  - bias pre-loaded into MFMA accumulator init (no epilogue adds)
//  - __float2bfloat16 (HW cvt) instead of 5-op manual RNE in hot epilogue
//  - launch_bounds(512,4) to keep VGPR <= 128

#define NE    8
#define FIN   90
#define HD    256
#define NOUT  4
#define XC    93          // 3 + FIN columns in x

#define MT        64      // points per block
#define NTHREADS  512     // 8 waves: 2 (wr) x 4 (wc)
#define HSTR      264     // LDS h stride (bf16 elems), +8 pad

#define KQ1   3           // ceil(90/32) -> K padded to 96
#define KQH   8           // 256/32
#define NBH   16          // 256/16

#define W1_ELEMS (NE*NBH*KQ1*512)   // 196608
#define W2_ELEMS (NE*NBH*KQH*512)   // 524288
#define WO_ELEMS (NE*KQH*512)       // 32768  (OUT padded 4->16)

typedef __attribute__((ext_vector_type(8))) short bf16x8;
typedef __attribute__((ext_vector_type(4))) float f32x4;

__device__ __forceinline__ unsigned short f2bf(float f) {   // cold path only
  union { float f; uint32_t u; } v; v.f = f;
  v.u += 0x7fffu + ((v.u >> 16) & 1u);   // RNE
  return (unsigned short)(v.u >> 16);
}

// ---------------------------------------------------------------------------
// Weight conversion: f32 [e][k][n] -> bf16 fragments [frag][lane][8] where
// frag = (e*NBH + nb)*KQ + kq, element (lane,j) = W[k = kq*32+(lane>>4)*8+j]
//                                                  [n = nb*16+(lane&15)].
// Exactly the mfma_f32_16x16x32_bf16 B-operand layout: one coalesced 16B/lane.
// ---------------------------------------------------------------------------
__global__ __launch_bounds__(256)
void convert_weights(const float* __restrict__ W1, const float* __restrict__ W2,
                     const float* __restrict__ W3, const float* __restrict__ Wo,
                     unsigned short* __restrict__ ws) {
  int idx = blockIdx.x * 256 + threadIdx.x;
  int j = idx & 7;
  int lane = (idx >> 3) & 63;
  int n16 = lane & 15;
  int kof = ((lane >> 4) << 3) + j;
  if (idx < W1_ELEMS) {
    int f = idx >> 9;
    int kq = f % KQ1; f /= KQ1;
    int nb = f % NBH; int e = f / NBH;
    int n = nb*16 + n16, k = kq*32 + kof;
    float v = (k < FIN) ? W1[(e*FIN + k)*HD + n] : 0.f;
    ws[idx] = f2bf(v);
  } else if (idx < W1_ELEMS + 2*W2_ELEMS) {
    int t = idx - W1_ELEMS;
    const float* W = (t < W2_ELEMS) ? W2 : W3;
    int u = (t < W2_ELEMS) ? t : (t - W2_ELEMS);
    int f = u >> 9;
    int kq = f % KQH; f /= KQH;
    int nb = f % NBH; int e = f / NBH;
    int n = nb*16 + n16, k = kq*32 + kof;
    ws[idx] = f2bf(W[(e*HD + k)*HD + n]);
  } else if (idx < W1_ELEMS + 2*W2_ELEMS + WO_ELEMS) {
    int t = idx - (W1_ELEMS + 2*W2_ELEMS);
    int f = t >> 9;
    int kq = f % KQH; int e = f / KQH;
    int k = kq*32 + kof;
    float v = (n16 < NOUT) ? Wo[(e*HD + k)*NOUT + n16] : 0.f;
    ws[idx] = f2bf(v);
  }
}

// Epilogue: relu + f32->bf16 (HW cvt), scatter C fragments into LDS h buffer.
// C/D layout (verified m89): col = lane&15, row = (lane>>4)*4 + reg.
__device__ __forceinline__ void store_h(f32x4 (&acc)[2][4], unsigned short* hout,
                                        int wr, int wc, int l15, int l4) {
#pragma unroll
  for (int nf = 0; nf < 4; ++nf) {
    int col = wc*64 + nf*16 + l15;
#pragma unroll
    for (int mf = 0; mf < 2; ++mf) {
      int row = wr*32 + mf*16 + l4*4;
#pragma unroll
      for (int j = 0; j < 4; ++j)
        *reinterpret_cast<__hip_bfloat16*>(&hout[(row + j)*HSTR + col]) =
            __float2bfloat16(fmaxf(acc[mf][nf][j], 0.f));
    }
  }
}

// One hidden layer: hin(64x256 bf16 LDS) @ W(256x256 frag bf16) + b -> relu -> hout
__device__ __forceinline__ void layerH(const unsigned short* hin, unsigned short* hout,
                                       const unsigned short* __restrict__ fw,
                                       const float* __restrict__ bias,
                                       int wr, int wc, int l15, int l4, int lane) {
  f32x4 acc[2][4];
#pragma unroll
  for (int nf = 0; nf < 4; ++nf) {
    float bv = bias[wc*64 + nf*16 + l15];      // bias folded into acc init
#pragma unroll
    for (int mf = 0; mf < 2; ++mf)
      acc[mf][nf] = f32x4{bv, bv, bv, bv};
  }

#pragma unroll
  for (int kq = 0; kq < KQH; ++kq) {
    bf16x8 a[2];
#pragma unroll
    for (int mf = 0; mf < 2; ++mf)
      a[mf] = *(const bf16x8*)(hin + (wr*32 + mf*16 + l15)*HSTR + kq*32 + l4*8);
    const unsigned short* bp = fw + ((((wc*4)*KQH) + kq) << 9) + lane*8;
#pragma unroll
    for (int nf = 0; nf < 4; ++nf) {
      bf16x8 b = *(const bf16x8*)(bp + ((nf*KQH) << 9));
#pragma unroll
      for (int mf = 0; mf < 2; ++mf)
        acc[mf][nf] = __builtin_amdgcn_mfma_f32_16x16x32_bf16(a[mf], b, acc[mf][nf], 0, 0, 0);
    }
  }
  store_h(acc, hout, wr, wc, l15, l4);
}

__global__ __launch_bounds__(NTHREADS, 4)
void meganerf_fused(const float* __restrict__ x, const float* __restrict__ cent,
                    const float* __restrict__ b1, const float* __restrict__ b2,
                    const float* __restrict__ b3, const float* __restrict__ bo,
                    const unsigned short* __restrict__ wf,
                    float* __restrict__ out) {
  __shared__ unsigned short hA[MT * HSTR];     // 33792 B
  __shared__ unsigned short hB[MT * HSTR];     // 33792 B
  __shared__ float wcl[MT * NE];               // 2048 B
  __shared__ float oacc[MT * NOUT];            // 1024 B   -> total 70656 B

  const int tid = threadIdx.x;
  const int lane = tid & 63;
  const int wv = tid >> 6;      // 0..7
  const int wr = wv >> 2;       // row group 0..1 (32 rows each)
  const int wc = wv & 3;        // col group 0..3 (64 cols each)
  const int l15 = lane & 15, l4 = lane >> 4;
  const int row0 = blockIdx.x * MT;

  // --- cluster weights (strict IEEE f32, no contraction: must bit-match np) ---
  if (tid < MT) {
    const int p = row0 + tid;
    float px = x[p*XC + 1], py = x[p*XC + 2];
    float d[NE]; float mind = 3.4e38f;
#pragma unroll
    for (int e = 0; e < NE; ++e) {
      float dx = px - cent[e*3 + 1];
      float dy = py - cent[e*3 + 2];
      d[e] = __fsqrt_rn(__fmul_rn(dx, dx) + __fmul_rn(dy, dy));
      mind = fminf(mind, d[e]);
    }
    float m = 1.5f * mind, s = 0.f, inv[NE];
#pragma unroll
    for (int e = 0; e < NE; ++e) {
      float iv = (d[e] > m) ? 0.f : 1.f / (d[e] + 1e-8f);
      inv[e] = iv; s += iv;
    }
#pragma unroll
    for (int e = 0; e < NE; ++e) wcl[tid*NE + e] = inv[e] / s;
  }
  if (tid < MT*NOUT) oacc[tid] = 0.f;

  // --- X fragments in registers (A-operand layout), reused across all experts ---
  bf16x8 xf[2][KQ1];
  {
    const int rbase = row0 + wr*32;
#pragma unroll
    for (int mf = 0; mf < 2; ++mf) {
      const float* src = x + (size_t)(rbase + mf*16 + l15)*XC + 3;
#pragma unroll
      for (int kq = 0; kq < KQ1; ++kq) {
        int kb = kq*32 + l4*8;
        bf16x8 v;
#pragma unroll
        for (int j = 0; j < 8; ++j) {
          float f = (kb + j < FIN) ? src[kb + j] : 0.f;
          v[j] = (short)f2bf(f);
        }
        xf[mf][kq] = v;
      }
    }
  }
  __syncthreads();

  const unsigned short* fw1 = wf;
  const unsigned short* fw2 = wf + W1_ELEMS;
  const unsigned short* fw3 = fw2 + W2_ELEMS;
  const unsigned short* fwo = fw3 + W2_ELEMS;

  for (int e = 0; e < NE; ++e) {
    // ---- layer 1: X(64x96) @ W1 -> relu -> hA ----
    {
      f32x4 acc[2][4];
#pragma unroll
      for (int nf = 0; nf < 4; ++nf) {
        float bv = b1[e*HD + wc*64 + nf*16 + l15];
#pragma unroll
        for (int mf = 0; mf < 2; ++mf)
          acc[mf][nf] = f32x4{bv, bv, bv, bv};
      }
#pragma unroll
      for (int kq = 0; kq < KQ1; ++kq) {
        const unsigned short* bp = fw1 + (((e*NBH + wc*4)*KQ1 + kq) << 9) + lane*8;
#pragma unroll
        for (int nf = 0; nf < 4; ++nf) {
          bf16x8 b = *(const bf16x8*)(bp + ((nf*KQ1) << 9));
#pragma unroll
          for (int mf = 0; mf < 2; ++mf)
            acc[mf][nf] = __builtin_amdgcn_mfma_f32_16x16x32_bf16(xf[mf][kq], b, acc[mf][nf], 0, 0, 0);
        }
      }
      store_h(acc, hA, wr, wc, l15, l4);
    }
    __syncthreads();

    // ---- layer 2: hA @ W2 -> relu -> hB ----
    layerH(hA, hB, fw2 + (e << 16), b2 + e*HD, wr, wc, l15, l4, lane);
    __syncthreads();

    // ---- layer 3: hB @ W3 -> relu -> hA ----
    layerH(hB, hA, fw3 + (e << 16), b3 + e*HD, wr, wc, l15, l4, lane);
    __syncthreads();

    // ---- layer 4 (OUT=4, padded to 16) + gated accumulation ----
    if (wv < 4) {
      f32x4 acc = {0.f, 0.f, 0.f, 0.f};
#pragma unroll
      for (int kq = 0; kq < KQH; ++kq) {
        bf16x8 a = *(const bf16x8*)(hA + (wv*16 + l15)*HSTR + kq*32 + l4*8);
        bf16x8 b = *(const bf16x8*)(fwo + ((e*KQH + kq) << 9) + lane*8);
        acc = __builtin_amdgcn_mfma_f32_16x16x32_bf16(a, b, acc, 0, 0, 0);
      }
      if (l15 < NOUT) {
        float bv = bo[e*NOUT + l15];
#pragma unroll
        for (int j = 0; j < 4; ++j) {
          int row = wv*16 + l4*4 + j;            // each thread owns its slots -> no race
          oacc[row*NOUT + l15] += wcl[row*NE + e] * (acc[j] + bv);
        }
      }
    }
    __syncthreads();   // protects hA (rewritten by next expert's layer 1)
  }

  if (tid < MT*NOUT)
    out[(size_t)row0*NOUT + tid] = oacc[tid];    // 256 contiguous f32, coalesced
}

extern "C" void kernel_launch(void* const* d_in, const int* in_sizes, int n_in,
                              void* d_out, int out_size, void* d_ws, size_t ws_size,
                              hipStream_t stream) {
  const float* x    = (const float*)d_in[0];
  const float* cent = (const float*)d_in[1];
  const float* W1   = (const float*)d_in[2];
  const float* b1   = (const float*)d_in[3];
  const float* W2   = (const float*)d_in[4];
  const float* b2   = (const float*)d_in[5];
  const float* W3   = (const float*)d_in[6];
  const float* b3   = (const float*)d_in[7];
  const float* Wo   = (const float*)d_in[8];
  const float* bo   = (const float*)d_in[9];
  float* out = (float*)d_out;
  unsigned short* wsb = (unsigned short*)d_ws;

  const int N = in_sizes[0] / XC;                 // 131072
  const int totalW = W1_ELEMS + 2*W2_ELEMS + WO_ELEMS;

  convert_weights<<<dim3((totalW + 255) / 256), dim3(256), 0, stream>>>(W1, W2, W3, Wo, wsb);
  meganerf_fused<<<dim3(N / MT), dim3(NTHREADS), 0, stream>>>(x, cent, b1, b2, b3, bo, wsb, out);
}

// Round 3
// 561.357 us; speedup vs baseline: 1.0946x; 1.0946x over previous
//
#include <hip/hip_runtime.h>
#include <hip/hip_bf16.h>
#include <stdint.h>

// MegaNeRF fused MoE-MLP for MI355X (gfx950).  Round 3.
// E=8 experts, MLP 90->256->256->256->4, N=131072 points, inverse-distance gating.
//
// Round-3: MT=128 (round-1 weight amortization) + SINGLE h LDS buffer.
// Layer output lives in registers before the LDS store, so hin can be
// overwritten in place: {MFMA reads} -> barrier -> {store} -> barrier.
// LDS 73.7 KB -> 2 blocks/CU (4 waves/SIMD) vs round-1's 1 block/CU.

#define NE    8
#define FIN   90
#define HD    256
#define NOUT  4
#define XC    93          // 3 + FIN columns in x

#define MT        128     // points per block
#define NTHREADS  512     // 8 waves: 2 (wr) x 4 (wc)
#define HSTR      264     // LDS h stride (bf16 elems), +8 pad

#define KQ1   3           // ceil(90/32) -> K padded to 96
#define KQH   8           // 256/32
#define NBH   16          // 256/16

#define W1_ELEMS (NE*NBH*KQ1*512)   // 196608
#define W2_ELEMS (NE*NBH*KQH*512)   // 524288
#define WO_ELEMS (NE*KQH*512)       // 32768  (OUT padded 4->16)

typedef __attribute__((ext_vector_type(8))) short bf16x8;
typedef __attribute__((ext_vector_type(4))) float f32x4;

__device__ __forceinline__ unsigned short f2bf(float f) {   // cold path only
  union { float f; uint32_t u; } v; v.f = f;
  v.u += 0x7fffu + ((v.u >> 16) & 1u);   // RNE
  return (unsigned short)(v.u >> 16);
}

// ---------------------------------------------------------------------------
// Weight conversion: f32 [e][k][n] -> bf16 fragments [frag][lane][8] where
// frag = (e*NBH + nb)*KQ + kq, element (lane,j) = W[k = kq*32+(lane>>4)*8+j]
//                                                  [n = nb*16+(lane&15)].
// Exactly the mfma_f32_16x16x32_bf16 B-operand layout: one coalesced 16B/lane.
// ---------------------------------------------------------------------------
__global__ __launch_bounds__(256)
void convert_weights(const float* __restrict__ W1, const float* __restrict__ W2,
                     const float* __restrict__ W3, const float* __restrict__ Wo,
                     unsigned short* __restrict__ ws) {
  int idx = blockIdx.x * 256 + threadIdx.x;
  int j = idx & 7;
  int lane = (idx >> 3) & 63;
  int n16 = lane & 15;
  int kof = ((lane >> 4) << 3) + j;
  if (idx < W1_ELEMS) {
    int f = idx >> 9;
    int kq = f % KQ1; f /= KQ1;
    int nb = f % NBH; int e = f / NBH;
    int n = nb*16 + n16, k = kq*32 + kof;
    float v = (k < FIN) ? W1[(e*FIN + k)*HD + n] : 0.f;
    ws[idx] = f2bf(v);
  } else if (idx < W1_ELEMS + 2*W2_ELEMS) {
    int t = idx - W1_ELEMS;
    const float* W = (t < W2_ELEMS) ? W2 : W3;
    int u = (t < W2_ELEMS) ? t : (t - W2_ELEMS);
    int f = u >> 9;
    int kq = f % KQH; f /= KQH;
    int nb = f % NBH; int e = f / NBH;
    int n = nb*16 + n16, k = kq*32 + kof;
    ws[idx] = f2bf(W[(e*HD + k)*HD + n]);
  } else if (idx < W1_ELEMS + 2*W2_ELEMS + WO_ELEMS) {
    int t = idx - (W1_ELEMS + 2*W2_ELEMS);
    int f = t >> 9;
    int kq = f % KQH; int e = f / KQH;
    int k = kq*32 + kof;
    float v = (n16 < NOUT) ? Wo[(e*HD + k)*NOUT + n16] : 0.f;
    ws[idx] = f2bf(v);
  }
}

// Epilogue: relu + f32->bf16 (HW cvt), scatter C fragments into LDS h buffer.
// C/D layout (verified m89): col = lane&15, row = (lane>>4)*4 + reg.
__device__ __forceinline__ void store_h(f32x4 (&acc)[4][4], unsigned short* hout,
                                        int wr, int wc, int l15, int l4) {
#pragma unroll
  for (int nf = 0; nf < 4; ++nf) {
    int col = wc*64 + nf*16 + l15;
#pragma unroll
    for (int mf = 0; mf < 4; ++mf) {
      int row = wr*64 + mf*16 + l4*4;
#pragma unroll
      for (int j = 0; j < 4; ++j)
        *reinterpret_cast<__hip_bfloat16*>(&hout[(row + j)*HSTR + col]) =
            __float2bfloat16(fmaxf(acc[mf][nf][j], 0.f));
    }
  }
}

// One hidden layer IN PLACE: h(128x256 bf16 LDS) @ W + b -> relu -> h.
// All reads happen in the MFMA loop (into registers), then barrier, then the
// same buffer is overwritten, then barrier.
__device__ __forceinline__ void layerH(unsigned short* h,
                                       const unsigned short* __restrict__ fw,
                                       const float* __restrict__ bias,
                                       int wr, int wc, int l15, int l4, int lane) {
  f32x4 acc[4][4];
#pragma unroll
  for (int nf = 0; nf < 4; ++nf) {
    float bv = bias[wc*64 + nf*16 + l15];      // bias folded into acc init
#pragma unroll
    for (int mf = 0; mf < 4; ++mf)
      acc[mf][nf] = f32x4{bv, bv, bv, bv};
  }

#pragma unroll
  for (int kq = 0; kq < KQH; ++kq) {
    bf16x8 a[4];
#pragma unroll
    for (int mf = 0; mf < 4; ++mf)
      a[mf] = *(const bf16x8*)(h + (wr*64 + mf*16 + l15)*HSTR + kq*32 + l4*8);
    const unsigned short* bp = fw + ((((wc*4)*KQH) + kq) << 9) + lane*8;
#pragma unroll
    for (int nf = 0; nf < 4; ++nf) {
      bf16x8 b = *(const bf16x8*)(bp + ((nf*KQH) << 9));
#pragma unroll
      for (int mf = 0; mf < 4; ++mf)
        acc[mf][nf] = __builtin_amdgcn_mfma_f32_16x16x32_bf16(a[mf], b, acc[mf][nf], 0, 0, 0);
    }
  }
  __syncthreads();                 // every wave finished reading h
  store_h(acc, h, wr, wc, l15, l4);
  __syncthreads();                 // h fully rewritten
}

__global__ __launch_bounds__(NTHREADS, 4)
void meganerf_fused(const float* __restrict__ x, const float* __restrict__ cent,
                    const float* __restrict__ b1, const float* __restrict__ b2,
                    const float* __restrict__ b3, const float* __restrict__ bo,
                    const unsigned short* __restrict__ wf,
                    float* __restrict__ out) {
  __shared__ unsigned short hA[MT * HSTR];     // 67584 B (single buffer)
  __shared__ float wcl[MT * NE];               // 4096 B
  __shared__ float oacc[MT * NOUT];            // 2048 B   -> total 73728 B

  const int tid = threadIdx.x;
  const int lane = tid & 63;
  const int wv = tid >> 6;      // 0..7
  const int wr = wv >> 2;       // row group 0..1 (64 rows each)
  const int wc = wv & 3;        // col group 0..3 (64 cols each)
  const int l15 = lane & 15, l4 = lane >> 4;
  const int row0 = blockIdx.x * MT;

  // --- cluster weights (strict IEEE f32, no contraction: must bit-match np) ---
  if (tid < MT) {
    const int p = row0 + tid;
    float px = x[p*XC + 1], py = x[p*XC + 2];
    float d[NE]; float mind = 3.4e38f;
#pragma unroll
    for (int e = 0; e < NE; ++e) {
      float dx = px - cent[e*3 + 1];
      float dy = py - cent[e*3 + 2];
      d[e] = __fsqrt_rn(__fmul_rn(dx, dx) + __fmul_rn(dy, dy));
      mind = fminf(mind, d[e]);
    }
    float m = 1.5f * mind, s = 0.f, inv[NE];
#pragma unroll
    for (int e = 0; e < NE; ++e) {
      float iv = (d[e] > m) ? 0.f : 1.f / (d[e] + 1e-8f);
      inv[e] = iv; s += iv;
    }
#pragma unroll
    for (int e = 0; e < NE; ++e) wcl[tid*NE + e] = inv[e] / s;
  }
  oacc[tid] = 0.f;   // MT*NOUT == 512 == blockDim

  // --- X fragments in registers (A-operand layout), reused across all experts ---
  bf16x8 xf[4][KQ1];
  {
    const int rbase = row0 + wr*64;
#pragma unroll
    for (int mf = 0; mf < 4; ++mf) {
      const float* src = x + (size_t)(rbase + mf*16 + l15)*XC + 3;
#pragma unroll
      for (int kq = 0; kq < KQ1; ++kq) {
        int kb = kq*32 + l4*8;
        bf16x8 v;
#pragma unroll
        for (int j = 0; j < 8; ++j) {
          float f = (kb + j < FIN) ? src[kb + j] : 0.f;
          v[j] = (short)f2bf(f);
        }
        xf[mf][kq] = v;
      }
    }
  }
  __syncthreads();

  const unsigned short* fw1 = wf;
  const unsigned short* fw2 = wf + W1_ELEMS;
  const unsigned short* fw3 = fw2 + W2_ELEMS;
  const unsigned short* fwo = fw3 + W2_ELEMS;

  for (int e = 0; e < NE; ++e) {
    // ---- layer 1: X(128x96, registers) @ W1 -> relu -> hA ----
    // No LDS reads here; safe to store once past the end-of-expert barrier.
    {
      f32x4 acc[4][4];
#pragma unroll
      for (int nf = 0; nf < 4; ++nf) {
        float bv = b1[e*HD + wc*64 + nf*16 + l15];
#pragma unroll
        for (int mf = 0; mf < 4; ++mf)
          acc[mf][nf] = f32x4{bv, bv, bv, bv};
      }
#pragma unroll
      for (int kq = 0; kq < KQ1; ++kq) {
        const unsigned short* bp = fw1 + (((e*NBH + wc*4)*KQ1 + kq) << 9) + lane*8;
#pragma unroll
        for (int nf = 0; nf < 4; ++nf) {
          bf16x8 b = *(const bf16x8*)(bp + ((nf*KQ1) << 9));
#pragma unroll
          for (int mf = 0; mf < 4; ++mf)
            acc[mf][nf] = __builtin_amdgcn_mfma_f32_16x16x32_bf16(xf[mf][kq], b, acc[mf][nf], 0, 0, 0);
        }
      }
      store_h(acc, hA, wr, wc, l15, l4);
    }
    __syncthreads();

    // ---- layer 2, layer 3: in-place hA ----
    layerH(hA, fw2 + (e << 16), b2 + e*HD, wr, wc, l15, l4, lane);
    layerH(hA, fw3 + (e << 16), b3 + e*HD, wr, wc, l15, l4, lane);

    // ---- layer 4 (OUT=4, padded to 16) + gated accumulation; all 8 waves ----
    {
      f32x4 acc = {0.f, 0.f, 0.f, 0.f};
#pragma unroll
      for (int kq = 0; kq < KQH; ++kq) {
        bf16x8 a = *(const bf16x8*)(hA + (wv*16 + l15)*HSTR + kq*32 + l4*8);
        bf16x8 b = *(const bf16x8*)(fwo + ((e*KQH + kq) << 9) + lane*8);
        acc = __builtin_amdgcn_mfma_f32_16x16x32_bf16(a, b, acc, 0, 0, 0);
      }
      if (l15 < NOUT) {
        float bv = bo[e*NOUT + l15];
#pragma unroll
        for (int j = 0; j < 4; ++j) {
          int row = wv*16 + l4*4 + j;            // each thread owns its slots -> no race
          oacc[row*NOUT + l15] += wcl[row*NE + e] * (acc[j] + bv);
        }
      }
    }
    __syncthreads();   // L4 reads of hA done; next expert's L1 may rewrite hA
  }

  out[(size_t)row0*NOUT + tid] = oacc[tid];      // 512 contiguous f32, coalesced
}

extern "C" void kernel_launch(void* const* d_in, const int* in_sizes, int n_in,
                              void* d_out, int out_size, void* d_ws, size_t ws_size,
                              hipStream_t stream) {
  const float* x    = (const float*)d_in[0];
  const float* cent = (const float*)d_in[1];
  const float* W1   = (const float*)d_in[2];
  const float* b1   = (const float*)d_in[3];
  const float* W2   = (const float*)d_in[4];
  const float* b2   = (const float*)d_in[5];
  const float* W3   = (const float*)d_in[6];
  const float* b3   = (const float*)d_in[7];
  const float* Wo   = (const float*)d_in[8];
  const float* bo   = (const float*)d_in[9];
  float* out = (float*)d_out;
  unsigned short* wsb = (unsigned short*)d_ws;

  const int N = in_sizes[0] / XC;                 // 131072
  const int totalW = W1_ELEMS + 2*W2_ELEMS + WO_ELEMS;

  convert_weights<<<dim3((totalW + 255) / 256), dim3(256), 0, stream>>>(W1, W2, W3, Wo, wsb);
  meganerf_fused<<<dim3(N / MT), dim3(NTHREADS), 0, stream>>>(x, cent, b1, b2, b3, bo, wsb, out);
}

// Round 4
// 451.513 us; speedup vs baseline: 1.3609x; 1.2433x over previous
//
#include <hip/hip_runtime.h>
#include <hip/hip_bf16.h>
#include <stdint.h>

// MegaNeRF fused MoE-MLP for MI355X (gfx950).  Round 4.
// E=8 experts, MLP 90->256->256->256->4, N=131072 points, inverse-distance gating.
//
// Round-4: identical to round-3 (MT=128, single in-place h LDS buffer, 73.7 KB
// -> 2 blocks/CU) EXCEPT __launch_bounds__(512,2).  Round-3's (512,4) capped
// VGPRs at 64 (observed) and spilled ~1 GB/dispatch to scratch (FETCH_SIZE
// 45 MB -> 648 MB).  (512,2) caps at 128; natural allocation is ~124 (round-1
// evidence), so no spill and still 4 waves/SIMD.

#define NE    8
#define FIN   90
#define HD    256
#define NOUT  4
#define XC    93          // 3 + FIN columns in x

#define MT        128     // points per block
#define NTHREADS  512     // 8 waves: 2 (wr) x 4 (wc)
#define HSTR      264     // LDS h stride (bf16 elems), +8 pad

#define KQ1   3           // ceil(90/32) -> K padded to 96
#define KQH   8           // 256/32
#define NBH   16          // 256/16

#define W1_ELEMS (NE*NBH*KQ1*512)   // 196608
#define W2_ELEMS (NE*NBH*KQH*512)   // 524288
#define WO_ELEMS (NE*KQH*512)       // 32768  (OUT padded 4->16)

typedef __attribute__((ext_vector_type(8))) short bf16x8;
typedef __attribute__((ext_vector_type(4))) float f32x4;

__device__ __forceinline__ unsigned short f2bf(float f) {   // cold path only
  union { float f; uint32_t u; } v; v.f = f;
  v.u += 0x7fffu + ((v.u >> 16) & 1u);   // RNE
  return (unsigned short)(v.u >> 16);
}

// ---------------------------------------------------------------------------
// Weight conversion: f32 [e][k][n] -> bf16 fragments [frag][lane][8] where
// frag = (e*NBH + nb)*KQ + kq, element (lane,j) = W[k = kq*32+(lane>>4)*8+j]
//                                                  [n = nb*16+(lane&15)].
// Exactly the mfma_f32_16x16x32_bf16 B-operand layout: one coalesced 16B/lane.
// ---------------------------------------------------------------------------
__global__ __launch_bounds__(256)
void convert_weights(const float* __restrict__ W1, const float* __restrict__ W2,
                     const float* __restrict__ W3, const float* __restrict__ Wo,
                     unsigned short* __restrict__ ws) {
  int idx = blockIdx.x * 256 + threadIdx.x;
  int j = idx & 7;
  int lane = (idx >> 3) & 63;
  int n16 = lane & 15;
  int kof = ((lane >> 4) << 3) + j;
  if (idx < W1_ELEMS) {
    int f = idx >> 9;
    int kq = f % KQ1; f /= KQ1;
    int nb = f % NBH; int e = f / NBH;
    int n = nb*16 + n16, k = kq*32 + kof;
    float v = (k < FIN) ? W1[(e*FIN + k)*HD + n] : 0.f;
    ws[idx] = f2bf(v);
  } else if (idx < W1_ELEMS + 2*W2_ELEMS) {
    int t = idx - W1_ELEMS;
    const float* W = (t < W2_ELEMS) ? W2 : W3;
    int u = (t < W2_ELEMS) ? t : (t - W2_ELEMS);
    int f = u >> 9;
    int kq = f % KQH; f /= KQH;
    int nb = f % NBH; int e = f / NBH;
    int n = nb*16 + n16, k = kq*32 + kof;
    ws[idx] = f2bf(W[(e*HD + k)*HD + n]);
  } else if (idx < W1_ELEMS + 2*W2_ELEMS + WO_ELEMS) {
    int t = idx - (W1_ELEMS + 2*W2_ELEMS);
    int f = t >> 9;
    int kq = f % KQH; int e = f / KQH;
    int k = kq*32 + kof;
    float v = (n16 < NOUT) ? Wo[(e*HD + k)*NOUT + n16] : 0.f;
    ws[idx] = f2bf(v);
  }
}

// Epilogue: relu + f32->bf16 (HW cvt), scatter C fragments into LDS h buffer.
// C/D layout (verified m89): col = lane&15, row = (lane>>4)*4 + reg.
__device__ __forceinline__ void store_h(f32x4 (&acc)[4][4], unsigned short* hout,
                                        int wr, int wc, int l15, int l4) {
#pragma unroll
  for (int nf = 0; nf < 4; ++nf) {
    int col = wc*64 + nf*16 + l15;
#pragma unroll
    for (int mf = 0; mf < 4; ++mf) {
      int row = wr*64 + mf*16 + l4*4;
#pragma unroll
      for (int j = 0; j < 4; ++j)
        *reinterpret_cast<__hip_bfloat16*>(&hout[(row + j)*HSTR + col]) =
            __float2bfloat16(fmaxf(acc[mf][nf][j], 0.f));
    }
  }
}

// One hidden layer IN PLACE: h(128x256 bf16 LDS) @ W + b -> relu -> h.
// All reads happen in the MFMA loop (into registers), then barrier, then the
// same buffer is overwritten, then barrier.
__device__ __forceinline__ void layerH(unsigned short* h,
                                       const unsigned short* __restrict__ fw,
                                       const float* __restrict__ bias,
                                       int wr, int wc, int l15, int l4, int lane) {
  f32x4 acc[4][4];
#pragma unroll
  for (int nf = 0; nf < 4; ++nf) {
    float bv = bias[wc*64 + nf*16 + l15];      // bias folded into acc init
#pragma unroll
    for (int mf = 0; mf < 4; ++mf)
      acc[mf][nf] = f32x4{bv, bv, bv, bv};
  }

#pragma unroll
  for (int kq = 0; kq < KQH; ++kq) {
    bf16x8 a[4];
#pragma unroll
    for (int mf = 0; mf < 4; ++mf)
      a[mf] = *(const bf16x8*)(h + (wr*64 + mf*16 + l15)*HSTR + kq*32 + l4*8);
    const unsigned short* bp = fw + ((((wc*4)*KQH) + kq) << 9) + lane*8;
#pragma unroll
    for (int nf = 0; nf < 4; ++nf) {
      bf16x8 b = *(const bf16x8*)(bp + ((nf*KQH) << 9));
#pragma unroll
      for (int mf = 0; mf < 4; ++mf)
        acc[mf][nf] = __builtin_amdgcn_mfma_f32_16x16x32_bf16(a[mf], b, acc[mf][nf], 0, 0, 0);
    }
  }
  __syncthreads();                 // every wave finished reading h
  store_h(acc, h, wr, wc, l15, l4);
  __syncthreads();                 // h fully rewritten
}

__global__ __launch_bounds__(NTHREADS, 2)
void meganerf_fused(const float* __restrict__ x, const float* __restrict__ cent,
                    const float* __restrict__ b1, const float* __restrict__ b2,
                    const float* __restrict__ b3, const float* __restrict__ bo,
                    const unsigned short* __restrict__ wf,
                    float* __restrict__ out) {
  __shared__ unsigned short hA[MT * HSTR];     // 67584 B (single buffer)
  __shared__ float wcl[MT * NE];               // 4096 B
  __shared__ float oacc[MT * NOUT];            // 2048 B   -> total 73728 B

  const int tid = threadIdx.x;
  const int lane = tid & 63;
  const int wv = tid >> 6;      // 0..7
  const int wr = wv >> 2;       // row group 0..1 (64 rows each)
  const int wc = wv & 3;        // col group 0..3 (64 cols each)
  const int l15 = lane & 15, l4 = lane >> 4;
  const int row0 = blockIdx.x * MT;

  // --- cluster weights (strict IEEE f32, no contraction: must bit-match np) ---
  if (tid < MT) {
    const int p = row0 + tid;
    float px = x[p*XC + 1], py = x[p*XC + 2];
    float d[NE]; float mind = 3.4e38f;
#pragma unroll
    for (int e = 0; e < NE; ++e) {
      float dx = px - cent[e*3 + 1];
      float dy = py - cent[e*3 + 2];
      d[e] = __fsqrt_rn(__fmul_rn(dx, dx) + __fmul_rn(dy, dy));
      mind = fminf(mind, d[e]);
    }
    float m = 1.5f * mind, s = 0.f, inv[NE];
#pragma unroll
    for (int e = 0; e < NE; ++e) {
      float iv = (d[e] > m) ? 0.f : 1.f / (d[e] + 1e-8f);
      inv[e] = iv; s += iv;
    }
#pragma unroll
    for (int e = 0; e < NE; ++e) wcl[tid*NE + e] = inv[e] / s;
  }
  oacc[tid] = 0.f;   // MT*NOUT == 512 == blockDim

  // --- X fragments in registers (A-operand layout), reused across all experts ---
  bf16x8 xf[4][KQ1];
  {
    const int rbase = row0 + wr*64;
#pragma unroll
    for (int mf = 0; mf < 4; ++mf) {
      const float* src = x + (size_t)(rbase + mf*16 + l15)*XC + 3;
#pragma unroll
      for (int kq = 0; kq < KQ1; ++kq) {
        int kb = kq*32 + l4*8;
        bf16x8 v;
#pragma unroll
        for (int j = 0; j < 8; ++j) {
          float f = (kb + j < FIN) ? src[kb + j] : 0.f;
          v[j] = (short)f2bf(f);
        }
        xf[mf][kq] = v;
      }
    }
  }
  __syncthreads();

  const unsigned short* fw1 = wf;
  const unsigned short* fw2 = wf + W1_ELEMS;
  const unsigned short* fw3 = fw2 + W2_ELEMS;
  const unsigned short* fwo = fw3 + W2_ELEMS;

  for (int e = 0; e < NE; ++e) {
    // ---- layer 1: X(128x96, registers) @ W1 -> relu -> hA ----
    // No LDS reads here; safe to store once past the end-of-expert barrier.
    {
      f32x4 acc[4][4];
#pragma unroll
      for (int nf = 0; nf < 4; ++nf) {
        float bv = b1[e*HD + wc*64 + nf*16 + l15];
#pragma unroll
        for (int mf = 0; mf < 4; ++mf)
          acc[mf][nf] = f32x4{bv, bv, bv, bv};
      }
#pragma unroll
      for (int kq = 0; kq < KQ1; ++kq) {
        const unsigned short* bp = fw1 + (((e*NBH + wc*4)*KQ1 + kq) << 9) + lane*8;
#pragma unroll
        for (int nf = 0; nf < 4; ++nf) {
          bf16x8 b = *(const bf16x8*)(bp + ((nf*KQ1) << 9));
#pragma unroll
          for (int mf = 0; mf < 4; ++mf)
            acc[mf][nf] = __builtin_amdgcn_mfma_f32_16x16x32_bf16(xf[mf][kq], b, acc[mf][nf], 0, 0, 0);
        }
      }
      store_h(acc, hA, wr, wc, l15, l4);
    }
    __syncthreads();

    // ---- layer 2, layer 3: in-place hA ----
    layerH(hA, fw2 + (e << 16), b2 + e*HD, wr, wc, l15, l4, lane);
    layerH(hA, fw3 + (e << 16), b3 + e*HD, wr, wc, l15, l4, lane);

    // ---- layer 4 (OUT=4, padded to 16) + gated accumulation; all 8 waves ----
    {
      f32x4 acc = {0.f, 0.f, 0.f, 0.f};
#pragma unroll
      for (int kq = 0; kq < KQH; ++kq) {
        bf16x8 a = *(const bf16x8*)(hA + (wv*16 + l15)*HSTR + kq*32 + l4*8);
        bf16x8 b = *(const bf16x8*)(fwo + ((e*KQH + kq) << 9) + lane*8);
        acc = __builtin_amdgcn_mfma_f32_16x16x32_bf16(a, b, acc, 0, 0, 0);
      }
      if (l15 < NOUT) {
        float bv = bo[e*NOUT + l15];
#pragma unroll
        for (int j = 0; j < 4; ++j) {
          int row = wv*16 + l4*4 + j;            // each thread owns its slots -> no race
          oacc[row*NOUT + l15] += wcl[row*NE + e] * (acc[j] + bv);
        }
      }
    }
    __syncthreads();   // L4 reads of hA done; next expert's L1 may rewrite hA
  }

  out[(size_t)row0*NOUT + tid] = oacc[tid];      // 512 contiguous f32, coalesced
}

extern "C" void kernel_launch(void* const* d_in, const int* in_sizes, int n_in,
                              void* d_out, int out_size, void* d_ws, size_t ws_size,
                              hipStream_t stream) {
  const float* x    = (const float*)d_in[0];
  const float* cent = (const float*)d_in[1];
  const float* W1   = (const float*)d_in[2];
  const float* b1   = (const float*)d_in[3];
  const float* W2   = (const float*)d_in[4];
  const float* b2   = (const float*)d_in[5];
  const float* W3   = (const float*)d_in[6];
  const float* b3   = (const float*)d_in[7];
  const float* Wo   = (const float*)d_in[8];
  const float* bo   = (const float*)d_in[9];
  float* out = (float*)d_out;
  unsigned short* wsb = (unsigned short*)d_ws;

  const int N = in_sizes[0] / XC;                 // 131072
  const int totalW = W1_ELEMS + 2*W2_ELEMS + WO_ELEMS;

  convert_weights<<<dim3((totalW + 255) / 256), dim3(256), 0, stream>>>(W1, W2, W3, Wo, wsb);
  meganerf_fused<<<dim3(N / MT), dim3(NTHREADS), 0, stream>>>(x, cent, b1, b2, b3, bo, wsb, out);
}